// Round 4
// baseline (188.942 us; speedup 1.0000x reference)
//
#include <hip/hip_runtime.h>
#include <cstddef>

// DCT-II matrix (float32 cast of numpy's float64 values)
static constexpr float D8[8][8] = {
  { 0.35355339059327373f, 0.35355339059327373f, 0.35355339059327373f, 0.35355339059327373f,
    0.35355339059327373f, 0.35355339059327373f, 0.35355339059327373f, 0.35355339059327373f},
  { 0.4903926402016152f,  0.4157348061512726f,  0.27778511650980114f, 0.09754516100806417f,
   -0.09754516100806417f,-0.27778511650980114f,-0.4157348061512726f, -0.4903926402016152f},
  { 0.46193976625564337f, 0.19134171618254492f,-0.19134171618254492f,-0.46193976625564337f,
   -0.46193976625564337f,-0.19134171618254492f, 0.19134171618254492f, 0.46193976625564337f},
  { 0.4157348061512726f, -0.09754516100806417f,-0.4903926402016152f, -0.27778511650980114f,
    0.27778511650980114f, 0.4903926402016152f,  0.09754516100806417f,-0.4157348061512726f},
  { 0.35355339059327373f,-0.35355339059327373f,-0.35355339059327373f, 0.35355339059327373f,
    0.35355339059327373f,-0.35355339059327373f,-0.35355339059327373f, 0.35355339059327373f},
  { 0.27778511650980114f,-0.4903926402016152f,  0.09754516100806417f, 0.4157348061512726f,
   -0.4157348061512726f, -0.09754516100806417f, 0.4903926402016152f, -0.27778511650980114f},
  { 0.19134171618254492f,-0.46193976625564337f, 0.46193976625564337f,-0.19134171618254492f,
   -0.19134171618254492f, 0.46193976625564337f,-0.46193976625564337f, 0.19134171618254492f},
  { 0.09754516100806417f,-0.27778511650980114f, 0.4157348061512726f, -0.4903926402016152f,
    0.4903926402016152f, -0.4157348061512726f,  0.27778511650980114f,-0.09754516100806417f},
};

// Quality-95 quant tables: q = clamp(floor((base*10+50)/100), 1, 255)
static constexpr float QLt[8][8] = {
  {2,1,1,2,2,4,5,6},
  {1,1,1,2,3,6,6,6},
  {1,1,2,2,4,6,7,6},
  {1,2,2,3,5,9,8,6},
  {2,2,4,6,7,11,10,8},
  {2,4,6,6,8,10,11,9},
  {5,6,8,9,10,12,12,10},
  {7,9,10,10,11,10,10,10},
};
static constexpr float QCt[8][8] = {
  {2,2,2,5,10,10,10,10},
  {2,2,3,7,10,10,10,10},
  {2,3,6,10,10,10,10,10},
  {5,7,10,10,10,10,10,10},
  {10,10,10,10,10,10,10,10},
  {10,10,10,10,10,10,10,10},
  {10,10,10,10,10,10,10,10},
  {10,10,10,10,10,10,10,10},
};

static constexpr float C255  = (float)(1.0/255.0);  // fl(1/255): matches jnp's f32 divisor
static constexpr float RC255 = 1.0f / C255;         // correctly-rounded reciprocal (constexpr IEEE)

// Markstein exactly-rounded division by constant c with precomputed r = fl(1/c):
// bit-identical to IEEE x/c, 3 VALU ops.
__device__ __forceinline__ float exact_div(float x, float c, float r) {
  float q0 = x * r;
  float e  = fmaf(-c, q0, x);
  return fmaf(e, r, q0);
}

// u[k] = sum_j D8[k][j] * x[j]
__device__ __forceinline__ void dct8(const float x[8], float u[8]) {
  #pragma unroll
  for (int k = 0; k < 8; ++k) {
    float a = D8[k][0] * x[0];
    #pragma unroll
    for (int j = 1; j < 8; ++j) a += D8[k][j] * x[j];
    u[k] = a;
  }
}

// u[j] = sum_m x[m] * D8[m][j]
__device__ __forceinline__ void idct8(const float x[8], float u[8]) {
  #pragma unroll
  for (int j = 0; j < 8; ++j) {
    float a = x[0] * D8[0][j];
    #pragma unroll
    for (int m = 1; m < 8; ++m) a += x[m] * D8[m][j];
    u[j] = a;
  }
}

// In-register 8x8 transpose across an aligned 8-lane group, branch-free
// (divergent private-array stores defeat SROA -> scratch; round-1 lesson).
__device__ __forceinline__ void xpose8(float v[8], int lane) {
  #pragma unroll
  for (int s = 1; s < 8; s <<= 1) {
    const bool hi = (lane & s) != 0;
    #pragma unroll
    for (int r0 = 0; r0 < 8; ++r0) {
      if (r0 & s) continue;            // compile-time skip
      const int r1 = r0 | s;
      const float a = v[r0], b = v[r1];
      const float send = hi ? a : b;
      const float got  = __shfl_xor(send, s, 64);
      v[r0] = hi ? got : a;
      v[r1] = hi ? b   : got;
    }
  }
}

// Full per-block pipeline: row DCT -> transpose -> col DCT -> quant ->
// col IDCT -> transpose -> row IDCT. v holds spatial row `lane` in/out.
__device__ __forceinline__ void jblk8(float v[8], int lane,
                                      const float* QT, const float* RQ) {
  float u[8];
  dct8(v, u);
  xpose8(u, lane);
  dct8(u, v);
  float4 Q0 = *(const float4*)&QT[0];
  float4 Q1 = *(const float4*)&QT[4];
  float4 R0 = *(const float4*)&RQ[0];
  float4 R1 = *(const float4*)&RQ[4];
  float qv[8] = {Q0.x,Q0.y,Q0.z,Q0.w,Q1.x,Q1.y,Q1.z,Q1.w};
  float rv[8] = {R0.x,R0.y,R0.z,R0.w,R1.x,R1.y,R1.z,R1.w};
  #pragma unroll
  for (int m = 0; m < 8; ++m)
    v[m] = rintf(exact_div(v[m], qv[m], rv[m])) * qv[m];
  idct8(v, u);
  xpose8(u, lane);
  idct8(u, v);
}

// Tile: 32 rows x 128 cols. Grid (4, 16, 32), 256 threads.
// 32 groups of 8 lanes; each group runs 3 pipelines: 2 luma blocks + 1 chroma
// block — perfectly balanced, zero divergence, 3-way ILP per thread.
// Luma never touches LDS: global -> regs -> DCT pipeline -> regs -> global.
__global__ __launch_bounds__(256) void jpeg_rt(const float* __restrict__ in,
                                               float* __restrict__ out)
{
  __shared__ __align__(16) float Cbp[16][68];   // half-res chroma planes
  __shared__ __align__(16) float Crp[16][68];   // (stride 68: <=2-way aliasing)
  __shared__ __align__(16) float QTs[2][8][8];  // [plane][col l][row m] = Q[m][l]
  __shared__ __align__(16) float RQs[2][8][8];  // correctly-rounded 1/Q

  const int t   = threadIdx.x;
  const int g   = t >> 3;       // group 0..31
  const int l   = t & 7;        // lane-in-group = row within 8x8 block
  const int ar  = g >> 4;       // luma block-row of pipeline A (0..1)
  const int ac  = g & 15;       // luma block-col (0..15)
  const int tx  = blockIdx.x;   // 0..3
  const int ty  = blockIdx.y;   // 0..15
  const int img = blockIdx.z;   // 0..31

  if (t < 128) {
    const int pl = t >> 6, i = (t >> 3) & 7, m = t & 7;
    const float q = pl ? QCt[m][i] : QLt[m][i];
    QTs[pl][i][m] = q;
    RQs[pl][i][m] = 1.0f / q;
  }

  const size_t imgbase = (size_t)img * (512*512);
  const int rowA = ar*8 + l;              // 0..15 (pipeline B adds +16)
  const int col0 = tx*128 + ac*8;

  float vA[8], vB[8];

  // ---------------- stage A: load 2 luma rows, color convert, emit chroma
  #pragma unroll
  for (int rr = 0; rr < 2; ++rr) {
    const int r = rowA + rr*16;
    const float* rp = in + (imgbase + (size_t)(ty*32 + r)*512 + col0)*3;
    float4 P0 = ((const float4*)rp)[0];
    float4 P1 = ((const float4*)rp)[1];
    float4 P2 = ((const float4*)rp)[2];
    float4 P3 = ((const float4*)rp)[3];
    float4 P4 = ((const float4*)rp)[4];
    float4 P5 = ((const float4*)rp)[5];
    float px[24] = {P0.x,P0.y,P0.z,P0.w,P1.x,P1.y,P1.z,P1.w,
                    P2.x,P2.y,P2.z,P2.w,P3.x,P3.y,P3.z,P3.w,
                    P4.x,P4.y,P4.z,P4.w,P5.x,P5.y,P5.z,P5.w};
    float yv[8], cbv[8], crv[8];
    #pragma unroll
    for (int p = 0; p < 8; ++p) {
      float rc = fminf(fmaxf(floorf(exact_div(px[3*p+0], C255, RC255)), 0.0f), 255.0f);
      float gc = fminf(fmaxf(floorf(exact_div(px[3*p+1], C255, RC255)), 0.0f), 255.0f);
      float bc = fminf(fmaxf(floorf(exact_div(px[3*p+2], C255, RC255)), 0.0f), 255.0f);
      float y  =  0.299f*rc + 0.587f*gc + 0.114f*bc;
      float cb = -0.168736f*rc - 0.331264f*gc + 0.5f*bc + 128.0f;
      float cr =  0.5f*rc - 0.418688f*gc - 0.081312f*bc + 128.0f;
      yv[p]  = y - 128.0f;
      cbv[p] = cb;
      crv[p] = cr;
    }
    // horizontal pair sums (same order as reference: (c00+c01)+(c10+c11))
    float hcb[4], hcr[4];
    #pragma unroll
    for (int k = 0; k < 4; ++k) {
      hcb[k] = cbv[2*k] + cbv[2*k+1];
      hcr[k] = crv[2*k] + crv[2*k+1];
    }
    // vertical pair: lanes l and l^1 hold rows 2i and 2i+1 of this region
    float ocb[4], ocr[4];
    #pragma unroll
    for (int k = 0; k < 4; ++k) {
      ocb[k] = __shfl_xor(hcb[k], 1, 64);
      ocr[k] = __shfl_xor(hcr[k], 1, 64);
    }
    if ((l & 1) == 0) {                 // even lane = top row of the pair
      const int crow = r >> 1;          // rr=0: 0..7, rr=1: 8..15
      *(float4*)&Cbp[crow][ac*4] = make_float4(
        (hcb[0]+ocb[0])*0.25f - 128.0f, (hcb[1]+ocb[1])*0.25f - 128.0f,
        (hcb[2]+ocb[2])*0.25f - 128.0f, (hcb[3]+ocb[3])*0.25f - 128.0f);
      *(float4*)&Crp[crow][ac*4] = make_float4(
        (hcr[0]+ocr[0])*0.25f - 128.0f, (hcr[1]+ocr[1])*0.25f - 128.0f,
        (hcr[2]+ocr[2])*0.25f - 128.0f, (hcr[3]+ocr[3])*0.25f - 128.0f);
    }
    #pragma unroll
    for (int p = 0; p < 8; ++p) {
      if (rr == 0) vA[p] = yv[p]; else vB[p] = yv[p];
    }
  }
  __syncthreads();   // chroma planes complete (also covers QTs init)

  // ---------------- phase B: three independent pipelines per thread
  jblk8(vA, l, &QTs[0][l][0], &RQs[0][l][0]);
  jblk8(vB, l, &QTs[0][l][0], &RQs[0][l][0]);
  {
    const int pl  = g >> 4;             // 0 = Cb, 1 = Cr (PLANE selector only)
    const int cg  = g & 15;
    const int cbr = cg >> 3, cbc = cg & 7;
    float* plane = pl ? &Crp[0][0] : &Cbp[0][0];
    float* rowp  = plane + (cbr*8 + l)*68 + cbc*8;
    float4 L0 = *(const float4*)&rowp[0];
    float4 L1 = *(const float4*)&rowp[4];
    float vC[8] = {L0.x,L0.y,L0.z,L0.w,L1.x,L1.y,L1.z,L1.w};
    // Round-3 bug: table index was `pl`, so Cb (pl=0) got the LUMA table.
    // Both chroma planes use the chroma table QTs[1]/RQs[1].
    jblk8(vC, l, &QTs[1][l][0], &RQs[1][l][0]);
    *(float4*)&rowp[0] = make_float4(vC[0],vC[1],vC[2],vC[3]);
    *(float4*)&rowp[4] = make_float4(vC[4],vC[5],vC[6],vC[7]);
  }
  __syncthreads();   // chroma rec complete

  // ---------------- output: luma rec still in regs; upsample chroma from LDS
  #pragma unroll
  for (int rr = 0; rr < 2; ++rr) {
    const int r = rowA + rr*16;
    const int crow = r >> 1;
    float4 CbF = *(const float4*)&Cbp[crow][ac*4];
    float4 CrF = *(const float4*)&Crp[crow][ac*4];
    float cbq[4] = {CbF.x,CbF.y,CbF.z,CbF.w};
    float crq[4] = {CrF.x,CrF.y,CrF.z,CrF.w};
    float ov[24];
    #pragma unroll
    for (int p = 0; p < 8; ++p) {
      float y2  = (rr ? vB[p] : vA[p]) + 128.0f;
      float cb2 = cbq[p>>1] + 128.0f;
      float cr2 = crq[p>>1] + 128.0f;
      float r2 = y2 + 1.402f*(cr2 - 128.0f);
      float g2 = y2 - 0.344136f*(cb2 - 128.0f) - 0.714136f*(cr2 - 128.0f);
      float b2 = y2 + 1.772f*(cb2 - 128.0f);
      ov[3*p+0] = exact_div(rintf(fminf(fmaxf(r2, 0.0f), 255.0f)), 255.0f, C255);
      ov[3*p+1] = exact_div(rintf(fminf(fmaxf(g2, 0.0f), 255.0f)), 255.0f, C255);
      ov[3*p+2] = exact_div(rintf(fminf(fmaxf(b2, 0.0f), 255.0f)), 255.0f, C255);
    }
    float* op = out + (imgbase + (size_t)(ty*32 + r)*512 + col0)*3;
    ((float4*)op)[0] = make_float4(ov[0], ov[1], ov[2], ov[3]);
    ((float4*)op)[1] = make_float4(ov[4], ov[5], ov[6], ov[7]);
    ((float4*)op)[2] = make_float4(ov[8], ov[9], ov[10],ov[11]);
    ((float4*)op)[3] = make_float4(ov[12],ov[13],ov[14],ov[15]);
    ((float4*)op)[4] = make_float4(ov[16],ov[17],ov[18],ov[19]);
    ((float4*)op)[5] = make_float4(ov[20],ov[21],ov[22],ov[23]);
  }
}

extern "C" void kernel_launch(void* const* d_in, const int* in_sizes, int n_in,
                              void* d_out, int out_size, void* d_ws, size_t ws_size,
                              hipStream_t stream) {
  (void)in_sizes; (void)n_in; (void)d_ws; (void)ws_size; (void)out_size;
  const float* x = (const float*)d_in[0];
  float* out = (float*)d_out;
  dim3 grid(4, 16, 32);   // W/128, H/32, B
  jpeg_rt<<<grid, dim3(256), 0, stream>>>(x, out);
}